// Round 1
// baseline (3684.967 us; speedup 1.0000x reference)
//
#include <hip/hip_runtime.h>
#include <hip/hip_bf16.h>
#include <cstdint>
#include <cstddef>

// ---------------- problem constants ----------------
#define B_TOT   8192
#define T_TOT   128
#define ROWS    32          // batch rows per block
#define THREADS 512         // 8 waves

typedef __bf16 bf16x8 __attribute__((ext_vector_type(8)));
typedef float  f32x4  __attribute__((ext_vector_type(4)));

// ---------------- ws layout (bytes) ----------------
// floats at start:
#define WSF_X0    0      // 64 f32 : x0 row (uniform across batch)
#define WSF_BCD   64     // 128 f32: drift  layer0 cond-bias
#define WSF_BCG   192    // 128 f32: diff   layer0 cond-bias
#define WSF_ROB   320    // 8 f32  : readout bias (ro_b + c0 @ ro_W[64:68])
#define WSB_SMALL 1536                    // 49152 bf16 : packed Wd0x|Wd1|Wg0x|Wg1
#define WSB_WD2   (WSB_SMALL + 49152*2)   // 8192 bf16  : packed Wd2
#define WSB_WG2   (WSB_WD2 + 8192*2)      // 131072 bf16: packed Wg2
#define WSB_TOTAL (WSB_WG2 + 131072*2)

__device__ __forceinline__ unsigned short f2bf(float v){
  union { float f; unsigned u; } x; x.f = v;
  unsigned r = (x.u + 0x7FFFu + ((x.u >> 16) & 1u)) >> 16;
  return (unsigned short)r;
}
__device__ __forceinline__ float fexp2(float x){ return __builtin_amdgcn_exp2f(x); }
__device__ __forceinline__ float frcp (float x){ return __builtin_amdgcn_rcpf(x); }
__device__ __forceinline__ float lipswish(float x){
  float e = fexp2(-1.44269504088896340f * x);          // 2^(-x*log2 e) = e^-x
  return 0.909f * x * frcp(1.0f + e);
}
__device__ __forceinline__ float tanhfast(float x){
  float e = fexp2(2.88539008177792681f * x);           // e^(2x)
  return 1.0f - 2.0f * frcp(e + 1.0f);
}
__device__ __forceinline__ f32x4 mfma16(bf16x8 a, bf16x8 b, f32x4 c){
  return __builtin_amdgcn_mfma_f32_16x16x32_bf16(a, b, c, 0, 0, 0);
}
// B^T-fragment read from a row-major [32][K] bf16 LDS tile with XOR swizzle.
// lane supplies B[k=(lg*8+kc*32)+j][n=brow]  == act[brow][k]
__device__ __forceinline__ bf16x8 lds_bfrag(const unsigned short* buf, int rowBytes,
                                            int brow, int kByte){
  int off = brow * rowBytes + kByte;
  off ^= (brow & 7) << 4;
  return *(const bf16x8*)((const char*)buf + off);
}

// ============================================================
// prep kernel: fold c0/t into biases, pack weights to fragment
// layout: packed[(ot*KC+kc)*64 + lane]*8 + j = W[kc*32+(lane>>4)*8+j][ot*16+(lane&15)]
// ============================================================
__global__ void prep_kernel(const float* __restrict__ cond,
    const float* __restrict__ drW0, const float* __restrict__ drb0,
    const float* __restrict__ drW1, const float* __restrict__ drW2,
    const float* __restrict__ diW0, const float* __restrict__ dib0,
    const float* __restrict__ diW1, const float* __restrict__ diW2,
    const float* __restrict__ initW, const float* __restrict__ initb,
    const float* __restrict__ roW,  const float* __restrict__ rob,
    char* __restrict__ ws)
{
  float* wsf = (float*)ws;
  unsigned short* wsm = (unsigned short*)(ws + WSB_SMALL);
  unsigned short* wd2 = (unsigned short*)(ws + WSB_WD2);
  unsigned short* wg2 = (unsigned short*)(ws + WSB_WG2);
  int tid = blockIdx.x * blockDim.x + threadIdx.x;
  int nth = gridDim.x * blockDim.x;

  for (int h = tid; h < 64; h += nth){
    float s = initb[h];
    #pragma unroll
    for (int i = 0; i < 16; i++) s += initW[i*64 + h];
    #pragma unroll
    for (int c = 0; c < 4; c++) s += cond[c] * initW[(16+c)*64 + h];
    wsf[WSF_X0 + h] = s;
  }
  for (int j = tid; j < 128; j += nth){
    float sd = drb0[j], sg = dib0[j];
    #pragma unroll
    for (int c = 0; c < 4; c++){
      sd += cond[c] * drW0[(65+c)*128 + j];
      sg += cond[c] * diW0[(65+c)*128 + j];
    }
    wsf[WSF_BCD + j] = sd; wsf[WSF_BCG + j] = sg;
  }
  for (int d = tid; d < 8; d += nth){
    float s = rob[d];
    #pragma unroll
    for (int c = 0; c < 4; c++) s += cond[c] * roW[(64+c)*8 + d];
    wsf[WSF_ROB + d] = s;
  }
  // small weights: frags: [0,16)=Wd0x(KC=2,ot8) [16,48)=Wd1(KC=4,ot8)
  //                [48,64)=Wg0x(KC=2,ot8) [64,96)=Wg1(KC=4,ot8)
  for (int u = tid; u < 49152; u += nth){
    int j = u & 7, lane = (u >> 3) & 63, frag = u >> 9;
    int k8 = ((lane >> 4) << 3) + j, o16 = lane & 15;
    float v;
    if (frag < 16)      { int kc = frag & 1,      ot = frag >> 1;      v = drW0[(1 + kc*32 + k8)*128 + ot*16 + o16]; }
    else if (frag < 48) { int f = frag - 16; int kc = f & 3, ot = f >> 2; v = drW1[(kc*32 + k8)*128 + ot*16 + o16]; }
    else if (frag < 64) { int f = frag - 48; int kc = f & 1, ot = f >> 1; v = diW0[(1 + kc*32 + k8)*128 + ot*16 + o16]; }
    else                { int f = frag - 64; int kc = f & 3, ot = f >> 2; v = diW1[(kc*32 + k8)*128 + ot*16 + o16]; }
    wsm[u] = f2bf(v);
  }
  for (int u = tid; u < 8192; u += nth){   // Wd2 [128x64], KC=4, ot 0..3
    int j = u & 7, lane = (u >> 3) & 63, frag = u >> 9, kc = frag & 3, ot = frag >> 2;
    wd2[u] = f2bf(drW2[(kc*32 + ((lane>>4)<<3) + j)*64 + ot*16 + (lane & 15)]);
  }
  for (int u = tid; u < 131072; u += nth){ // Wg2 [128x1024], KC=4, ot 0..63
    int j = u & 7, lane = (u >> 3) & 63, frag = u >> 9, kc = frag & 3, ot = frag >> 2;
    wg2[u] = f2bf(diW2[(kc*32 + ((lane>>4)<<3) + j)*1024 + ot*16 + (lane & 15)]);
  }
}

// ============================================================
// main persistent kernel: 256 blocks x 512 threads (8 waves),
// 32 batch rows per block, whole time loop on-chip.
// ============================================================
__global__ __launch_bounds__(THREADS, 2) void sde_kernel(
    const float* __restrict__ dW,  const float* __restrict__ tsg,
    const float* __restrict__ drW0, const float* __restrict__ diW0, // row0 = w0t
    const float* __restrict__ bd1, const float* __restrict__ bg1,
    const float* __restrict__ bd2, const float* __restrict__ bg2,
    const float* __restrict__ roWg,
    const char* __restrict__ ws, float* __restrict__ out)
{
  __shared__ unsigned short smallW[49152];  // 96 KB packed weights
  __shared__ unsigned short z1buf[2048];    // [32][64] bf16, swizzled (also y-scratch)
  __shared__ unsigned short h1d[4096];      // [32][128] bf16 swz | doubles as bT f32[64][32] swz
  __shared__ unsigned short h1g[4096];      // [32][128] bf16 swz | doubles as aT f32[64][32] swz
  __shared__ unsigned short h2d[4096];
  __shared__ unsigned short h2g[4096];
  __shared__ float f1T[2048];               // [64][32] f32, idx = h*32 + (brow^(h&31))
  __shared__ float roWs[512];               // ro_W[0:64][0:8]
  __shared__ float tsbuf[128];
  __shared__ float robiasS[8];

  const float* wsf = (const float*)ws;
  const unsigned short* wsSmall = (const unsigned short*)(ws + WSB_SMALL);
  const unsigned short* wsWd2   = (const unsigned short*)(ws + WSB_WD2);
  const unsigned short* wsWg2   = (const unsigned short*)(ws + WSB_WG2);

  const int tid = threadIdx.x;
  const int w  = tid >> 6;        // wave 0..7
  const int l  = tid & 63;        // lane
  const int lg = l >> 4;          // 0..3 (k-group / C row-group)
  const int li = l & 15;          // 0..15 (batch col in C)
  const int B0 = blockIdx.x * ROWS;
  const int row   = tid >> 4;         // 0..31  (elementwise mapping)
  const int hbase = (tid & 15) << 2;  // 0..60

  // ---- init: stage small weights + tables into LDS ----
  {
    const uint4* src = (const uint4*)wsSmall;
    uint4* dst = (uint4*)smallW;
    for (int i = tid; i < 6144; i += THREADS) dst[i] = src[i];
    for (int i = tid; i < 128; i += THREADS) tsbuf[i] = tsg[i];
    for (int i = tid; i < 512; i += THREADS) roWs[i] = roWg[i];
    if (tid < 8) robiasS[tid] = wsf[WSF_ROB + tid];
  }

  // ---- per-thread state (4 h-slots each) ----
  float y[4], z[4], fz[4], az[4];
  #pragma unroll
  for (int j = 0; j < 4; j++){ float v = wsf[WSF_X0 + hbase + j]; y[j] = v; z[j] = v; }

  auto writeZ = [&](){
    unsigned lo = (unsigned)f2bf(z[0]) | ((unsigned)f2bf(z[1]) << 16);
    unsigned hi = (unsigned)f2bf(z[2]) | ((unsigned)f2bf(z[3]) << 16);
    int off = row*128 + (hbase << 1); off ^= (row & 7) << 4;
    uint2 v; v.x = lo; v.y = hi;
    *(uint2*)((char*)z1buf + off) = v;
  };
  writeZ();   // z1buf <- x0

  // ---- weight fragments kept in registers for the whole loop ----
  bf16x8 wd2f[4];
  #pragma unroll
  for (int kc = 0; kc < 4; kc++)
    wd2f[kc] = *(const bf16x8*)(wsWd2 + (size_t)(((w>>1)*4 + kc)*64 + l)*8);
  f32x4 bd2r = *(const f32x4*)(bd2 + (w>>1)*16 + lg*4);
  bf16x8 wg2f[8][4];
  #pragma unroll
  for (int ot = 0; ot < 8; ot++)
    #pragma unroll
    for (int kc = 0; kc < 4; kc++)
      wg2f[ot][kc] = *(const bf16x8*)(wsWg2 + (size_t)(((w*8 + ot)*4 + kc)*64 + l)*8);

  __syncthreads();

  // ---- one full MLP pipeline evaluation at (tval, z1buf) ----
  auto PIPE = [&](float tval, int kdwc, int kdwn){
    // ---- P1: layer0 drift+diff : [128 out]x[32] , K=64 ----
    {
      bf16x8 zb[2][2];
      #pragma unroll
      for (int bm = 0; bm < 2; bm++)
        #pragma unroll
        for (int kc = 0; kc < 2; kc++)
          zb[bm][kc] = lds_bfrag(z1buf, 128, bm*16 + li, (kc*32 + lg*8)*2);
      #pragma unroll
      for (int p = 0; p < 2; p++){
        const int base = p ? 24576 : 0;
        f32x4 bcv = *(const f32x4*)(wsf + (p ? WSF_BCG : WSF_BCD) + w*16 + lg*4);
        f32x4 wtv = *(const f32x4*)((p ? diW0 : drW0) + w*16 + lg*4);
        bf16x8 af0 = *(const bf16x8*)(smallW + base + ((w*2 + 0)*64 + l)*8);
        bf16x8 af1 = *(const bf16x8*)(smallW + base + ((w*2 + 1)*64 + l)*8);
        unsigned short* hout = p ? h1g : h1d;
        #pragma unroll
        for (int bm = 0; bm < 2; bm++){
          f32x4 acc = {0.f,0.f,0.f,0.f};
          acc = mfma16(af0, zb[bm][0], acc);
          acc = mfma16(af1, zb[bm][1], acc);
          int brow = bm*16 + li;
          #pragma unroll
          for (int r = 0; r < 4; r++){
            float xx = acc[r] + bcv[r] + tval*wtv[r];
            int off = brow*256 + ((w*16 + lg*4 + r) << 1); off ^= (brow & 7) << 4;
            *(unsigned short*)((char*)hout + off) = f2bf(lipswish(xx));
          }
        }
      }
    }
    __syncthreads();
    // ---- P2: layer1 : waves 0-3 drift, 4-7 diff ----
    {
      const int p = w >> 2;
      const unsigned short* hin  = p ? h1g : h1d;
      unsigned short*       hout = p ? h2g : h2d;
      const float* b1 = p ? bg1 : bd1;
      const int base = p ? 32768 : 8192;
      const int ot0 = (w & 3)*2;
      bf16x8 hb[2][4];
      #pragma unroll
      for (int bm = 0; bm < 2; bm++)
        #pragma unroll
        for (int kc = 0; kc < 4; kc++)
          hb[bm][kc] = lds_bfrag(hin, 256, bm*16 + li, (kc*32 + lg*8)*2);
      #pragma unroll
      for (int o2 = 0; o2 < 2; o2++){
        const int ot = ot0 + o2;
        bf16x8 af[4];
        #pragma unroll
        for (int kc = 0; kc < 4; kc++)
          af[kc] = *(const bf16x8*)(smallW + base + ((ot*4 + kc)*64 + l)*8);
        f32x4 b1v = *(const f32x4*)(b1 + ot*16 + lg*4);
        #pragma unroll
        for (int bm = 0; bm < 2; bm++){
          f32x4 acc = {0.f,0.f,0.f,0.f};
          #pragma unroll
          for (int kc = 0; kc < 4; kc++) acc = mfma16(af[kc], hb[bm][kc], acc);
          int brow = bm*16 + li;
          #pragma unroll
          for (int r = 0; r < 4; r++){
            float xx = acc[r] + b1v[r];
            int off = brow*256 + ((ot*16 + lg*4 + r) << 1); off ^= (brow & 7) << 4;
            *(unsigned short*)((char*)hout + off) = f2bf(lipswish(xx));
          }
        }
      }
    }
    __syncthreads();
    // ---- P3: drift L2 (f) + diff L2 (g, contracted with dW) ----
    {
      { // drift: subtile (ot=w>>1, bm=w&1)
        const int ot = w >> 1, bm = w & 1, brow = bm*16 + li;
        bf16x8 db[4];
        #pragma unroll
        for (int kc = 0; kc < 4; kc++) db[kc] = lds_bfrag(h2d, 256, brow, (kc*32 + lg*8)*2);
        f32x4 acc = {0.f,0.f,0.f,0.f};
        #pragma unroll
        for (int kc = 0; kc < 4; kc++) acc = mfma16(wd2f[kc], db[kc], acc);
        #pragma unroll
        for (int r = 0; r < 4; r++){
          int h = ot*16 + lg*4 + r;
          f1T[h*32 + (brow ^ (h & 31))] = tanhfast(acc[r] + bd2r[r]);
        }
      }
      { // diffusion: each wave h = w*8 .. w*8+7
        float* bT = (float*)h1d;
        float* aT = (float*)h1g;
        const f32x4* dc = (const f32x4*)(dW + (size_t)kdwc * 131072);
        const f32x4* dn = (const f32x4*)(dW + (size_t)kdwn * 131072);
        #pragma unroll
        for (int bm = 0; bm < 2; bm++){
          const int brow = bm*16 + li;
          bf16x8 gb[4];
          #pragma unroll
          for (int kc = 0; kc < 4; kc++) gb[kc] = lds_bfrag(h2g, 256, brow, (kc*32 + lg*8)*2);
          const int rr = B0 + brow;
          f32x4 dwc = dc[(size_t)rr*4 + lg];   // dw[row][m], m = lg*4+r
          f32x4 dwn = dn[(size_t)rr*4 + lg];
          #pragma unroll
          for (int ot = 0; ot < 8; ot++){
            const int h = w*8 + ot;
            f32x4 bgv = *(const f32x4*)(bg2 + h*16 + lg*4);
            f32x4 acc = {0.f,0.f,0.f,0.f};
            #pragma unroll
            for (int kc = 0; kc < 4; kc++) acc = mfma16(wg2f[ot][kc], gb[kc], acc);
            float bs = 0.f, as_ = 0.f;
            #pragma unroll
            for (int r = 0; r < 4; r++){
              float g = tanhfast(acc[r] + bgv[r]);
              bs  += g * dwc[r];
              as_ += g * dwn[r];
            }
            bs  += __shfl_xor(bs, 16);  bs  += __shfl_xor(bs, 32);
            as_ += __shfl_xor(as_, 16); as_ += __shfl_xor(as_, 32);
            const int idx = h*32 + (brow ^ (h & 31));
            if (lg == 0)      bT[idx] = bs;
            else if (lg == 1) aT[idx] = as_;
          }
        }
      }
    }
  };

  auto writeOut = [&](int t){
    float part[8];
    #pragma unroll
    for (int d = 0; d < 8; d++) part[d] = 0.f;
    #pragma unroll
    for (int j = 0; j < 4; j++){
      float yv = y[j];
      const float* rw = roWs + (hbase + j)*8;
      #pragma unroll
      for (int d = 0; d < 8; d++) part[d] += yv * rw[d];
    }
    #pragma unroll
    for (int s = 1; s < 16; s <<= 1)
      #pragma unroll
      for (int d = 0; d < 8; d++) part[d] += __shfl_xor(part[d], s);
    if (li < 9){
      float v = (li == 0) ? tsbuf[t] : (part[li-1] + robiasS[li-1]);
      out[(size_t)(B0 + row)*1152 + (size_t)t*9 + li] = v;
    }
  };

  // ---- prologue: f0, g0 at (t0, x0) ----
  PIPE(tsbuf[0], 0, 0);
  __syncthreads();
  {
    #pragma unroll
    for (int j = 0; j < 4; j++){
      int h = hbase + j; int idx = h*32 + (row ^ (h & 31));
      fz[j] = f1T[idx];
      az[j] = ((const float*)h1g)[idx];      // a0 = g0 @ dW[0]
    }
    writeOut(0);                             // t=0 : x0 @ roW
    float dt0 = tsbuf[1] - tsbuf[0];
    #pragma unroll
    for (int j = 0; j < 4; j++) z[j] = 2.f*y[j] - z[j] + fz[j]*dt0 + az[j];  // z_1
    writeZ();
  }
  __syncthreads();

  // ---- main time loop ----
  for (int k = 0; k < 127; k++){
    PIPE(tsbuf[k+1], k, (k < 126) ? (k+1) : 126);
    __syncthreads();
    float f1[4], bb[4], an[4];
    #pragma unroll
    for (int j = 0; j < 4; j++){
      int h = hbase + j; int idx = h*32 + (row ^ (h & 31));
      f1[j] = f1T[idx];
      bb[j] = ((const float*)h1d)[idx];
      an[j] = ((const float*)h1g)[idx];
    }
    float dtk = tsbuf[k+1] - tsbuf[k];
    #pragma unroll
    for (int j = 0; j < 4; j++){
      y[j] += 0.5f*dtk*(fz[j] + f1[j]) + 0.5f*(az[j] + bb[j]);
      fz[j] = f1[j]; az[j] = an[j];
    }
    writeOut(k+1);
    if (k < 126){
      float dtn = tsbuf[k+2] - tsbuf[k+1];
      #pragma unroll
      for (int j = 0; j < 4; j++) z[j] = 2.f*y[j] - z[j] + fz[j]*dtn + az[j];
      writeZ();
    }
    __syncthreads();
  }
}

// ============================================================
extern "C" void kernel_launch(void* const* d_in, const int* in_sizes, int n_in,
                              void* d_out, int out_size, void* d_ws, size_t ws_size,
                              hipStream_t stream)
{
  const float* ts   = (const float*)d_in[0];
  const float* cond = (const float*)d_in[1];
  const float* dW   = (const float*)d_in[2];
  const float* drW0 = (const float*)d_in[3];
  const float* drb0 = (const float*)d_in[4];
  const float* drW1 = (const float*)d_in[5];
  const float* drb1 = (const float*)d_in[6];
  const float* drW2 = (const float*)d_in[7];
  const float* drb2 = (const float*)d_in[8];
  const float* diW0 = (const float*)d_in[9];
  const float* dib0 = (const float*)d_in[10];
  const float* diW1 = (const float*)d_in[11];
  const float* dib1 = (const float*)d_in[12];
  const float* diW2 = (const float*)d_in[13];
  const float* dib2 = (const float*)d_in[14];
  const float* initW= (const float*)d_in[15];
  const float* initb= (const float*)d_in[16];
  const float* roW  = (const float*)d_in[17];
  const float* rob  = (const float*)d_in[18];
  char* ws = (char*)d_ws;
  if (ws_size < (size_t)WSB_TOTAL) return;

  prep_kernel<<<dim3(256), dim3(256), 0, stream>>>(
      cond, drW0, drb0, drW1, drW2, diW0, dib0, diW1, diW2,
      initW, initb, roW, rob, ws);
  sde_kernel<<<dim3(256), dim3(THREADS), 0, stream>>>(
      dW, ts, drW0, diW0, drb1, dib1, drb2, dib2, roW, ws, (float*)d_out);
}

// Round 2
// 1210.708 us; speedup vs baseline: 3.0436x; 3.0436x over previous
//
#include <hip/hip_runtime.h>
#include <hip/hip_bf16.h>
#include <cstdint>
#include <cstddef>

// ---------------- problem constants ----------------
#define B_TOT   8192
#define T_TOT   128
#define ROWS    32          // batch rows per block
#define THREADS 512         // 8 waves

typedef __bf16 bf16x8 __attribute__((ext_vector_type(8)));
typedef float  f32x4  __attribute__((ext_vector_type(4)));

// ---------------- ws layout (bytes) ----------------
#define WSF_X0    0      // 64 f32 : x0 row (uniform across batch)
#define WSF_BCD   64     // 128 f32: drift  layer0 cond-bias
#define WSF_BCG   192    // 128 f32: diff   layer0 cond-bias
#define WSF_ROB   320    // 8 f32  : readout bias (ro_b + c0 @ ro_W[64:68])
#define WSB_SMALL 1536                    // 49152 bf16 : packed Wd0x|Wd1|Wg0x|Wg1
#define WSB_WD2   (WSB_SMALL + 49152*2)   // 8192 bf16  : packed Wd2
#define WSB_WG2   (WSB_WD2 + 8192*2)      // 131072 bf16: packed Wg2
#define WSB_TOTAL (WSB_WG2 + 131072*2)

__device__ __forceinline__ unsigned short f2bf(float v){
  union { float f; unsigned u; } x; x.f = v;
  unsigned r = (x.u + 0x7FFFu + ((x.u >> 16) & 1u)) >> 16;
  return (unsigned short)r;
}
// hardware packed f32->bf16 (RNE), 1 inst for 2 values
__device__ __forceinline__ unsigned cvtpk(float lo, float hi){
  unsigned r;
  asm("v_cvt_pk_bf16_f32 %0, %1, %2" : "=v"(r) : "v"(lo), "v"(hi));
  return r;
}
__device__ __forceinline__ float fexp2(float x){ return __builtin_amdgcn_exp2f(x); }
__device__ __forceinline__ float frcp (float x){ return __builtin_amdgcn_rcpf(x); }
__device__ __forceinline__ float lipswish(float x){
  float e = fexp2(-1.44269504088896340f * x);          // e^-x
  return 0.909f * x * frcp(1.0f + e);
}
__device__ __forceinline__ float tanhfast(float x){
  float e = fexp2(2.88539008177792681f * x);           // e^(2x)
  return 1.0f - 2.0f * frcp(e + 1.0f);
}
__device__ __forceinline__ f32x4 mfma16(bf16x8 a, bf16x8 b, f32x4 c){
  return __builtin_amdgcn_mfma_f32_16x16x32_bf16(a, b, c, 0, 0, 0);
}
// B^T-fragment read from a row-major [32][K] bf16 LDS tile with XOR swizzle.
__device__ __forceinline__ bf16x8 lds_bfrag(const unsigned short* buf, int rowBytes,
                                            int brow, int kByte){
  int off = brow * rowBytes + kByte;
  off ^= (brow & 7) << 4;
  return *(const bf16x8*)((const char*)buf + off);
}

// ============================================================
// prep kernel: fold c0/t into biases, pack weights to fragment
// layout: packed[(ot*KC+kc)*64 + lane]*8 + j = W[kc*32+(lane>>4)*8+j][ot*16+(lane&15)]
// ============================================================
__global__ void prep_kernel(const float* __restrict__ cond,
    const float* __restrict__ drW0, const float* __restrict__ drb0,
    const float* __restrict__ drW1, const float* __restrict__ drW2,
    const float* __restrict__ diW0, const float* __restrict__ dib0,
    const float* __restrict__ diW1, const float* __restrict__ diW2,
    const float* __restrict__ initW, const float* __restrict__ initb,
    const float* __restrict__ roW,  const float* __restrict__ rob,
    char* __restrict__ ws)
{
  float* wsf = (float*)ws;
  unsigned short* wsm = (unsigned short*)(ws + WSB_SMALL);
  unsigned short* wd2 = (unsigned short*)(ws + WSB_WD2);
  unsigned short* wg2 = (unsigned short*)(ws + WSB_WG2);
  int tid = blockIdx.x * blockDim.x + threadIdx.x;
  int nth = gridDim.x * blockDim.x;

  for (int h = tid; h < 64; h += nth){
    float s = initb[h];
    #pragma unroll
    for (int i = 0; i < 16; i++) s += initW[i*64 + h];
    #pragma unroll
    for (int c = 0; c < 4; c++) s += cond[c] * initW[(16+c)*64 + h];
    wsf[WSF_X0 + h] = s;
  }
  for (int j = tid; j < 128; j += nth){
    float sd = drb0[j], sg = dib0[j];
    #pragma unroll
    for (int c = 0; c < 4; c++){
      sd += cond[c] * drW0[(65+c)*128 + j];
      sg += cond[c] * diW0[(65+c)*128 + j];
    }
    wsf[WSF_BCD + j] = sd; wsf[WSF_BCG + j] = sg;
  }
  for (int d = tid; d < 8; d += nth){
    float s = rob[d];
    #pragma unroll
    for (int c = 0; c < 4; c++) s += cond[c] * roW[(64+c)*8 + d];
    wsf[WSF_ROB + d] = s;
  }
  for (int u = tid; u < 49152; u += nth){
    int j = u & 7, lane = (u >> 3) & 63, frag = u >> 9;
    int k8 = ((lane >> 4) << 3) + j, o16 = lane & 15;
    float v;
    if (frag < 16)      { int kc = frag & 1,      ot = frag >> 1;      v = drW0[(1 + kc*32 + k8)*128 + ot*16 + o16]; }
    else if (frag < 48) { int f = frag - 16; int kc = f & 3, ot = f >> 2; v = drW1[(kc*32 + k8)*128 + ot*16 + o16]; }
    else if (frag < 64) { int f = frag - 48; int kc = f & 1, ot = f >> 1; v = diW0[(1 + kc*32 + k8)*128 + ot*16 + o16]; }
    else                { int f = frag - 64; int kc = f & 3, ot = f >> 2; v = diW1[(kc*32 + k8)*128 + ot*16 + o16]; }
    wsm[u] = f2bf(v);
  }
  for (int u = tid; u < 8192; u += nth){   // Wd2 [128x64], KC=4, ot 0..3
    int j = u & 7, lane = (u >> 3) & 63, frag = u >> 9, kc = frag & 3, ot = frag >> 2;
    wd2[u] = f2bf(drW2[(kc*32 + ((lane>>4)<<3) + j)*64 + ot*16 + (lane & 15)]);
  }
  for (int u = tid; u < 131072; u += nth){ // Wg2 [128x1024], KC=4, ot 0..63
    int j = u & 7, lane = (u >> 3) & 63, frag = u >> 9, kc = frag & 3, ot = frag >> 2;
    wg2[u] = f2bf(diW2[(kc*32 + ((lane>>4)<<3) + j)*1024 + ot*16 + (lane & 15)]);
  }
}

// ============================================================
// main persistent kernel: 256 blocks x 512 threads (8 waves),
// 32 batch rows per block, whole time loop on-chip.
// Wg2 is STREAMED from L2 per ot-tile (register double-buffer),
// never register-resident -> no spills.
// ============================================================
__global__ __launch_bounds__(THREADS, 2) void sde_kernel(
    const float* __restrict__ dW,  const float* __restrict__ tsg,
    const float* __restrict__ drW0, const float* __restrict__ diW0, // row0 = t weights
    const float* __restrict__ bd1, const float* __restrict__ bg1,
    const float* __restrict__ bd2, const float* __restrict__ bg2,
    const float* __restrict__ roWg,
    const char* __restrict__ ws, float* __restrict__ out)
{
  __shared__ unsigned short smallW[49152];  // 96 KB packed weights
  __shared__ unsigned short z1buf[2048];    // [32][64] bf16, swizzled
  __shared__ unsigned short h1d[4096];      // [32][128] bf16 swz | doubles as bT f32[64][32]
  __shared__ unsigned short h1g[4096];      // [32][128] bf16 swz | doubles as aT f32[64][32]
  __shared__ unsigned short h2d[4096];
  __shared__ unsigned short h2g[4096];
  __shared__ float f1T[2048];               // [64][32] f32, idx = h*32 + (brow^(h&31))
  __shared__ float roWs[512];               // ro_W[0:64][0:8]
  __shared__ float tsbuf[128];
  __shared__ float bcdS[128], bcgS[128];    // layer0 cond biases
  __shared__ float wtdS[128], wtgS[128];    // layer0 t-row weights
  __shared__ float bd1S[128], bg1S[128];    // layer1 biases
  __shared__ float bg2S[1024];              // diff layer2 bias
  __shared__ float robiasS[8];

  const float* wsf = (const float*)ws;
  const unsigned short* wsSmall = (const unsigned short*)(ws + WSB_SMALL);
  const unsigned short* wsWd2   = (const unsigned short*)(ws + WSB_WD2);
  const unsigned short* wsWg2   = (const unsigned short*)(ws + WSB_WG2);

  const int tid = threadIdx.x;
  const int w  = tid >> 6;        // wave 0..7
  const int l  = tid & 63;        // lane
  const int lg = l >> 4;          // 0..3
  const int li = l & 15;          // 0..15
  const int B0 = blockIdx.x * ROWS;
  const int row   = tid >> 4;         // 0..31  (elementwise mapping)
  const int hbase = (tid & 15) << 2;  // 0..60

  // ---- init staging ----
  {
    const uint4* src = (const uint4*)wsSmall;
    uint4* dst = (uint4*)smallW;
    for (int i = tid; i < 6144; i += THREADS) dst[i] = src[i];
    for (int i = tid; i < 128; i += THREADS){
      tsbuf[i] = tsg[i];
      bcdS[i] = wsf[WSF_BCD + i]; bcgS[i] = wsf[WSF_BCG + i];
      wtdS[i] = drW0[i];          wtgS[i] = diW0[i];
      bd1S[i] = bd1[i];           bg1S[i] = bg1[i];
    }
    for (int i = tid; i < 512; i += THREADS) roWs[i] = roWg[i];
    for (int i = tid; i < 1024; i += THREADS) bg2S[i] = bg2[i];
    if (tid < 8) robiasS[tid] = wsf[WSF_ROB + tid];
  }

  // ---- per-thread state (4 h-slots each) ----
  float y[4], z[4], fz[4], az[4];
  #pragma unroll
  for (int j = 0; j < 4; j++){ float v = wsf[WSF_X0 + hbase + j]; y[j] = v; z[j] = v; }

  auto writeZ = [&](){
    unsigned lo = cvtpk(z[0], z[1]);
    unsigned hi = cvtpk(z[2], z[3]);
    int off = row*128 + (hbase << 1); off ^= (row & 7) << 4;
    uint2 v; v.x = lo; v.y = hi;
    *(uint2*)((char*)z1buf + off) = v;
  };
  writeZ();   // z1buf <- x0

  // drift L2 weights persistent (only 16 VGPRs)
  bf16x8 wd2f[4];
  #pragma unroll
  for (int kc = 0; kc < 4; kc++)
    wd2f[kc] = *(const bf16x8*)(wsWd2 + (size_t)(((w>>1)*4 + kc)*64 + l)*8);
  f32x4 bd2r = *(const f32x4*)(bd2 + (w>>1)*16 + lg*4);

  __syncthreads();

  // Wg2 fragment loader: wave w owns h = w*8 .. w*8+7
  auto ldwg = [&](int ot, int kc) -> bf16x8 {
    return *(const bf16x8*)(wsWg2 + ((((w*8 + ot)*4 + kc)*64 + l) << 3));
  };

  // ---- one full MLP pipeline evaluation at (tval, z1buf) ----
  auto PIPE = [&](float tval, int kdwc, int kdwn){
    // prefetch dW slices for P3 (HBM/L2, used much later)
    const f32x4* dc = (const f32x4*)(dW + (size_t)kdwc * 131072);
    const f32x4* dn = (const f32x4*)(dW + (size_t)kdwn * 131072);
    f32x4 dwc[2], dwn[2];
    dwc[0] = dc[(size_t)(B0 + li)*4 + lg];      dwc[1] = dc[(size_t)(B0 + 16 + li)*4 + lg];
    dwn[0] = dn[(size_t)(B0 + li)*4 + lg];      dwn[1] = dn[(size_t)(B0 + 16 + li)*4 + lg];

    // ---- P1: layer0 drift+diff : [128 out]x[32], K=64 ----
    {
      bf16x8 zb[2][2];
      #pragma unroll
      for (int bm = 0; bm < 2; bm++)
        #pragma unroll
        for (int kc = 0; kc < 2; kc++)
          zb[bm][kc] = lds_bfrag(z1buf, 128, bm*16 + li, (kc*32 + lg*8)*2);
      #pragma unroll
      for (int p = 0; p < 2; p++){
        const int base = p ? 24576 : 0;
        f32x4 bcv = *(const f32x4*)((p ? bcgS : bcdS) + w*16 + lg*4);
        f32x4 wtv = *(const f32x4*)((p ? wtgS : wtdS) + w*16 + lg*4);
        bf16x8 af0 = *(const bf16x8*)(smallW + base + ((w*2 + 0)*64 + l)*8);
        bf16x8 af1 = *(const bf16x8*)(smallW + base + ((w*2 + 1)*64 + l)*8);
        unsigned short* hout = p ? h1g : h1d;
        #pragma unroll
        for (int bm = 0; bm < 2; bm++){
          f32x4 acc = {0.f,0.f,0.f,0.f};
          acc = mfma16(af0, zb[bm][0], acc);
          acc = mfma16(af1, zb[bm][1], acc);
          int brow = bm*16 + li;
          float xx[4];
          #pragma unroll
          for (int r = 0; r < 4; r++) xx[r] = lipswish(acc[r] + bcv[r] + tval*wtv[r]);
          int off = brow*256 + ((w*16 + lg*4) << 1); off ^= (brow & 7) << 4;
          uint2 v; v.x = cvtpk(xx[0], xx[1]); v.y = cvtpk(xx[2], xx[3]);
          *(uint2*)((char*)hout + off) = v;
        }
      }
    }
    __syncthreads();
    // ---- P2: layer1 : waves 0-3 drift, 4-7 diff ----
    {
      const int p = w >> 2;
      const unsigned short* hin  = p ? h1g : h1d;
      unsigned short*       hout = p ? h2g : h2d;
      const float* b1 = p ? bg1S : bd1S;
      const int base = p ? 32768 : 8192;
      const int ot0 = (w & 3)*2;
      bf16x8 hb[2][4];
      #pragma unroll
      for (int bm = 0; bm < 2; bm++)
        #pragma unroll
        for (int kc = 0; kc < 4; kc++)
          hb[bm][kc] = lds_bfrag(hin, 256, bm*16 + li, (kc*32 + lg*8)*2);
      #pragma unroll
      for (int o2 = 0; o2 < 2; o2++){
        const int ot = ot0 + o2;
        bf16x8 af[4];
        #pragma unroll
        for (int kc = 0; kc < 4; kc++)
          af[kc] = *(const bf16x8*)(smallW + base + ((ot*4 + kc)*64 + l)*8);
        f32x4 b1v = *(const f32x4*)(b1 + ot*16 + lg*4);
        #pragma unroll
        for (int bm = 0; bm < 2; bm++){
          f32x4 acc = {0.f,0.f,0.f,0.f};
          #pragma unroll
          for (int kc = 0; kc < 4; kc++) acc = mfma16(af[kc], hb[bm][kc], acc);
          int brow = bm*16 + li;
          float xx[4];
          #pragma unroll
          for (int r = 0; r < 4; r++) xx[r] = lipswish(acc[r] + b1v[r]);
          int off = brow*256 + ((ot*16 + lg*4) << 1); off ^= (brow & 7) << 4;
          uint2 v; v.x = cvtpk(xx[0], xx[1]); v.y = cvtpk(xx[2], xx[3]);
          *(uint2*)((char*)hout + off) = v;
        }
      }
    }
    __syncthreads();
    // ---- P3: drift L2 (f) + diff L2 (g, contracted with dW) ----
    {
      float* bT = (float*)h1d;
      float* aT = (float*)h1g;
      // issue first Wg2 frag batch (L2) before drift compute hides latency
      bf16x8 fA[4], fB[4];
      #pragma unroll
      for (int kc = 0; kc < 4; kc++) fA[kc] = ldwg(0, kc);
      // g-layer1 output fragments for both bm (read once)
      bf16x8 gb[2][4];
      #pragma unroll
      for (int bm = 0; bm < 2; bm++)
        #pragma unroll
        for (int kc = 0; kc < 4; kc++)
          gb[bm][kc] = lds_bfrag(h2g, 256, bm*16 + li, (kc*32 + lg*8)*2);
      { // drift: subtile (ot=w>>1, bm=w&1)
        const int ot = w >> 1, bm = w & 1, brow = bm*16 + li;
        bf16x8 db[4];
        #pragma unroll
        for (int kc = 0; kc < 4; kc++) db[kc] = lds_bfrag(h2d, 256, brow, (kc*32 + lg*8)*2);
        f32x4 acc = {0.f,0.f,0.f,0.f};
        #pragma unroll
        for (int kc = 0; kc < 4; kc++) acc = mfma16(wd2f[kc], db[kc], acc);
        #pragma unroll
        for (int r = 0; r < 4; r++){
          int h = ot*16 + lg*4 + r;
          f1T[h*32 + (brow ^ (h & 31))] = tanhfast(acc[r] + bd2r[r]);
        }
      }
      // diffusion: wave handles h = w*8 .. w*8+7, Wg2 streamed, dbuf'd
      auto G2 = [&](int ot, const bf16x8* f){
        const int h = w*8 + ot;
        f32x4 bgv = *(const f32x4*)(bg2S + h*16 + lg*4);
        #pragma unroll
        for (int bm = 0; bm < 2; bm++){
          const int brow = bm*16 + li;
          f32x4 acc = {0.f,0.f,0.f,0.f};
          #pragma unroll
          for (int kc = 0; kc < 4; kc++) acc = mfma16(f[kc], gb[bm][kc], acc);
          float bs = 0.f, as_ = 0.f;
          #pragma unroll
          for (int r = 0; r < 4; r++){
            float g = tanhfast(acc[r] + bgv[r]);
            bs  += g * dwc[bm][r];
            as_ += g * dwn[bm][r];
          }
          bs  += __shfl_xor(bs, 16);  bs  += __shfl_xor(bs, 32);
          as_ += __shfl_xor(as_, 16); as_ += __shfl_xor(as_, 32);
          const int idx = h*32 + (brow ^ (h & 31));
          if (lg == 0)      bT[idx] = bs;
          else if (lg == 1) aT[idx] = as_;
        }
      };
      #pragma unroll 1
      for (int op = 0; op < 4; op++){
        const int ot0 = op*2;
        #pragma unroll
        for (int kc = 0; kc < 4; kc++) fB[kc] = ldwg(ot0 + 1, kc);
        G2(ot0, fA);
        if (op < 3){
          #pragma unroll
          for (int kc = 0; kc < 4; kc++) fA[kc] = ldwg(ot0 + 2, kc);
        }
        G2(ot0 + 1, fB);
      }
    }
  };

  auto writeOut = [&](int t){
    float part[8];
    #pragma unroll
    for (int d = 0; d < 8; d++) part[d] = 0.f;
    #pragma unroll
    for (int j = 0; j < 4; j++){
      float yv = y[j];
      const float* rw = roWs + (hbase + j)*8;
      #pragma unroll
      for (int d = 0; d < 8; d++) part[d] += yv * rw[d];
    }
    #pragma unroll
    for (int s = 1; s < 16; s <<= 1)
      #pragma unroll
      for (int d = 0; d < 8; d++) part[d] += __shfl_xor(part[d], s);
    if (li < 9){
      float v = (li == 0) ? tsbuf[t] : (part[li-1] + robiasS[li-1]);
      out[(size_t)(B0 + row)*1152 + (size_t)t*9 + li] = v;
    }
  };

  // ---- prologue: f0, g0 at (t0, x0) ----
  PIPE(tsbuf[0], 0, 0);
  __syncthreads();
  {
    #pragma unroll
    for (int j = 0; j < 4; j++){
      int h = hbase + j; int idx = h*32 + (row ^ (h & 31));
      fz[j] = f1T[idx];
      az[j] = ((const float*)h1g)[idx];      // a0 = g0 @ dW[0]
    }
    writeOut(0);
    float dt0 = tsbuf[1] - tsbuf[0];
    #pragma unroll
    for (int j = 0; j < 4; j++) z[j] = 2.f*y[j] - z[j] + fz[j]*dt0 + az[j];
    writeZ();
  }
  __syncthreads();

  // ---- main time loop ----
  for (int k = 0; k < 127; k++){
    PIPE(tsbuf[k+1], k, (k < 126) ? (k+1) : 126);
    __syncthreads();
    float f1[4], bb[4], an[4];
    #pragma unroll
    for (int j = 0; j < 4; j++){
      int h = hbase + j; int idx = h*32 + (row ^ (h & 31));
      f1[j] = f1T[idx];
      bb[j] = ((const float*)h1d)[idx];
      an[j] = ((const float*)h1g)[idx];
    }
    float dtk = tsbuf[k+1] - tsbuf[k];
    #pragma unroll
    for (int j = 0; j < 4; j++){
      y[j] += 0.5f*dtk*(fz[j] + f1[j]) + 0.5f*(az[j] + bb[j]);
      fz[j] = f1[j]; az[j] = an[j];
    }
    writeOut(k+1);
    if (k < 126){
      float dtn = tsbuf[k+2] - tsbuf[k+1];
      #pragma unroll
      for (int j = 0; j < 4; j++) z[j] = 2.f*y[j] - z[j] + fz[j]*dtn + az[j];
      writeZ();
    }
    __syncthreads();
  }
}

// ============================================================
extern "C" void kernel_launch(void* const* d_in, const int* in_sizes, int n_in,
                              void* d_out, int out_size, void* d_ws, size_t ws_size,
                              hipStream_t stream)
{
  const float* ts   = (const float*)d_in[0];
  const float* cond = (const float*)d_in[1];
  const float* dW   = (const float*)d_in[2];
  const float* drW0 = (const float*)d_in[3];
  const float* drb0 = (const float*)d_in[4];
  const float* drW1 = (const float*)d_in[5];
  const float* drb1 = (const float*)d_in[6];
  const float* drW2 = (const float*)d_in[7];
  const float* drb2 = (const float*)d_in[8];
  const float* diW0 = (const float*)d_in[9];
  const float* dib0 = (const float*)d_in[10];
  const float* diW1 = (const float*)d_in[11];
  const float* dib1 = (const float*)d_in[12];
  const float* diW2 = (const float*)d_in[13];
  const float* dib2 = (const float*)d_in[14];
  const float* initW= (const float*)d_in[15];
  const float* initb= (const float*)d_in[16];
  const float* roW  = (const float*)d_in[17];
  const float* rob  = (const float*)d_in[18];
  char* ws = (char*)d_ws;
  if (ws_size < (size_t)WSB_TOTAL) return;

  prep_kernel<<<dim3(256), dim3(256), 0, stream>>>(
      cond, drW0, drb0, drW1, drW2, diW0, dib0, diW1, diW2,
      initW, initb, roW, rob, ws);
  sde_kernel<<<dim3(256), dim3(THREADS), 0, stream>>>(
      dW, ts, drW0, diW0, drb1, dib1, drb2, dib2, roW, ws, (float*)d_out);
}